// Round 10
// baseline (99.044 us; speedup 1.0000x reference)
//
#include <hip/hip_runtime.h>
#include <utility>

// EquivariantProductBasisBlock (MACE-style) for gfx950 — round 21.
// R20: 98.04us (best). Kernel ~37.5us vs VALU floor ~10us; batched W
// prefetch in phase B gave -2.5us (mechanism right, magnitude small: each
// removed event buys ~40cyc once compiler hoisting is accounted).
// R21: same mechanism applied to phase A (the untreated half, ~80 load
// events/thread): (1) nf 18 scalar dwords -> 4x dwordx4 + 1x dwordx2
// (per-thread 72B is contiguous; align-4 vectors validated R16);
// (2) consumption-ordered weight packing wt[E][31][64] float4: slot = 2
// paths x 2 channels, slots in EXACT phase-A consumption order (constexpr
// replay of the CI loop); lanes = channel pairs -> 16B apart, coalesced
// 1KB/wave-load. 62 strided dwordx2 events -> 31 sequential dwordx4.
// Phase B byte-identical to R20. Predict: kernel ~30-33us, dur ~90-93.
// Falsifier: no movement -> phase-A event model dead -> timing probe next.

#define NN 4096
#define NC 128
#define NE 10

typedef float v2f __attribute__((ext_vector_type(2)));
typedef float f4u __attribute__((ext_vector_type(4), aligned(4)));

__device__ __forceinline__ v2f ld2(const float* p) {
  return *reinterpret_cast<const v2f*>(p);
}
__device__ __forceinline__ v2f cfma(float c, v2f x, v2f a) {  // a += c*x (splat c)
  v2f cc = {c, c};
  return __builtin_elementwise_fma(cc, x, a);
}
__device__ __forceinline__ v2f vfma(v2f w, v2f x, v2f a) {    // a += w*x
  return __builtin_elementwise_fma(w, x, a);
}

// ---------------------------- static_for ---------------------------------------
template<typename F, int... Is>
__device__ __forceinline__ void sfor_impl(F&& f, std::integer_sequence<int, Is...>) {
  (f(std::integral_constant<int, Is>{}), ...);
}
template<int N, typename F>
__device__ __forceinline__ void sfor(F&& f) {
  sfor_impl((F&&)f, std::make_integer_sequence<int, N>{});
}

// ---------------------------- CG metadata (constexpr) --------------------------
constexpr int T_L1c[19]  = {0,0,0,1,1,1,1,1,1,1,2,2,2,2,2,2,2,2,3};
constexpr int T_L2c[19]  = {0,1,2,0,1,1,1,2,2,2,0,1,1,1,2,2,2,2,2};
constexpr int T_L3c[19]  = {0,1,2,1,0,1,2,1,2,3,2,1,2,3,0,1,2,3,1};
constexpr int T_OFFc[19] = {0,1,10,35,44,53,80,125,170,245,350,375,420,495,600,625,700,825,1000};
constexpr int AOFFc[3]   = {0,1,4};

constexpr int P2U_L1c[7]  = {0,0,1,1,1,2,2};
constexpr int P2U_L2c[7]  = {0,1,1,1,2,2,2};
constexpr int P2U_LOc[7]  = {0,1,0,1,1,0,1};
constexpr int P2U_TBLc[7] = {0,1,4,5,7,14,15};
constexpr int P2U_WAc[7]  = {0,1,3,4,5,7,8};
constexpr int P2U_WBc[7]  = {-1,2,-1,-1,6,-1,-1};

constexpr int K_L1c[18]  = {0,0,0,1,1,1,1,1,1,1,2,2,2,2,2,2,2,2};
constexpr int K_L2c[18]  = {0,1,2,0,1,1,1,2,2,2,0,1,1,1,2,2,2,2};
constexpr int K_L12c[18] = {0,1,2,1,0,1,2,1,2,3,2,1,2,3,0,1,2,3};

constexpr int   TT_CANONc[18] = {0,1,2,1,4,5,6,7,8,9,2,7,8,9,14,15,16,17};
constexpr float TT_SGNc[18]   = {1,1,1,1,1,1,1,1,1,1,1,1,-1,1,1,1,1,1};
constexpr int CANONc[13] = {0,1,2,4,5,6,7,8,9,14,15,16,17};
constexpr int CONS2c[13] = {-1,3,10,-1,-1,-1,11,12,13,-1,-1,-1,-1};

constexpr int P3_STARTc[19] = {0,2,6,9,13,15,19,22,26,29,30,33,37,40,41,43,47,50,51};
constexpr int P3_L3c[51] = {
  0,1,  0,1,1,2,  1,2,2,  0,1,1,2,  0,1,  0,1,1,2,  1,2,2,  0,1,1,2,  1,2,2,
  2,  1,2,2,  0,1,1,2,  1,2,2,  2,  0,1,  0,1,1,2,  1,2,2,  2 };
constexpr int P3_LOc[51] = {
  0,1,  1,0,1,1,  1,0,1,  1,0,1,1,  0,1,  1,0,1,1,  1,0,1,  1,0,1,1,  1,0,1,
  1,  1,0,1,  1,0,1,1,  1,0,1,  1,  0,1,  1,0,1,1,  1,0,1,  1 };
constexpr int P3_TBLc[51] = {
  0,1,  3,4,5,7,  11,14,15,  3,4,5,7,  0,1,  3,4,5,7,  11,14,15,  3,4,5,7,
  11,14,15,  18,  11,14,15,  3,4,5,7,  11,14,15,  18,  0,1,  3,4,5,7,
  11,14,15,  18 };

// ---------------------------- weight pack order --------------------------------
// Global path index pi: 0..1 = w1, 2..10 = w2 j0..j8, 11..61 = w3 p0..p50.
// ord[] = pi list in EXACT phase-A consumption order (replays the CI loop);
// pos[] = inverse. Slot s holds paths ord[2s], ord[2s+1] for 2 channels.
struct PackO { int ord[62]; int pos[62]; };
constexpr PackO make_pack() {
  PackO P{};
  int k = 0;
  P.ord[k++] = 0; P.ord[k++] = 1;                    // w1
  for (int j = 0; j < 9; ++j) P.ord[k++] = 2 + j;    // w2 (consumed j0..j8)
  for (int ci = 0; ci < 13; ++ci) {                  // w3: replay CI loop
    const int tk = CANONc[ci];
    for (int p = P3_STARTc[tk]; p < P3_STARTc[tk + 1]; ++p) P.ord[k++] = 11 + p;
    const int td = CONS2c[ci];
    if (td >= 0)
      for (int p = P3_STARTc[td]; p < P3_STARTc[td + 1]; ++p) P.ord[k++] = 11 + p;
  }
  for (int i = 0; i < 62; ++i) P.pos[P.ord[i]] = i;
  return P;
}
constexpr PackO PK = make_pack();

// ---------------------------- constexpr CG computation -------------------------
constexpr double cfact(int n) { double r = 1.0; for (int i = 2; i <= n; ++i) r *= i; return r; }
constexpr double csqrt(double x) {
  if (x <= 0.0) return 0.0;
  double r = x > 1.0 ? x : 1.0;
  for (int i = 0; i < 64; ++i) r = 0.5 * (r + x / r);
  return r;
}
constexpr double su2cg(int j1, int m1, int j2, int m2, int j3, int m3) {
  if (m3 != m1 + m2) return 0.0;
  int vmin = -j1 + j2 + m3; if (-j1 + m1 > vmin) vmin = -j1 + m1; if (vmin < 0) vmin = 0;
  int vmax = j2 + j3 + m1; if (j3 - j1 + j2 < vmax) vmax = j3 - j1 + j2; if (j3 + m3 < vmax) vmax = j3 + m3;
  double C = csqrt((2.0 * j3 + 1.0)
                   * cfact(j3 + j1 - j2) * cfact(j3 - j1 + j2) * cfact(j1 + j2 - j3)
                   * cfact(j3 + m3) * cfact(j3 - m3)
                   / (cfact(j1 + j2 + j3 + 1) * cfact(j1 - m1) * cfact(j1 + m1)
                      * cfact(j2 - m2) * cfact(j2 + m2)));
  double S = 0.0;
  for (int v = vmin; v <= vmax; ++v) {
    double sgn = ((v + j2 + m2) & 1) ? -1.0 : 1.0;
    S += sgn * cfact(j2 + j3 + m1 - v) * cfact(j1 - m1 + v)
         / (cfact(v) * cfact(j3 - j1 + j2 - v) * cfact(j3 + m3 - v) * cfact(v + j1 - j2 - m3));
  }
  return C * S;
}

struct Cx { double re, im; };
constexpr Cx cxmul(Cx a, Cx b) { return Cx{a.re * b.re - a.im * b.im, a.re * b.im + a.im * b.re}; }
struct Row { int cnt; int col[2]; Cx v[2]; };

constexpr Row c2r_row(int l, int r) {
  Row out{0, {0, 0}, {{0, 0}, {0, 0}}};
  constexpr double is2 = 0.70710678118654752440;
  const int m = r - l;
  if (m < 0) {
    out.cnt = 2;
    out.col[0] = l - m; out.v[0] = Cx{is2, 0.0};
    out.col[1] = l + m; out.v[1] = Cx{0.0, -is2};
  } else if (m == 0) {
    out.cnt = 1; out.col[0] = l; out.v[0] = Cx{1.0, 0.0};
  } else {
    const double sgn = (m & 1) ? -1.0 : 1.0;
    out.cnt = 2;
    out.col[0] = l + m; out.v[0] = Cx{sgn * is2, 0.0};
    out.col[1] = l - m; out.v[1] = Cx{0.0, sgn * is2};
  }
  const int ph = l & 3;
  for (int a = 0; a < out.cnt; ++a) {
    Cx v = out.v[a];
    out.v[a] = (ph == 0) ? v
             : (ph == 1) ? Cx{v.im, -v.re}
             : (ph == 2) ? Cx{-v.re, -v.im}
                         : Cx{-v.im, v.re};
  }
  return out;
}

struct CGAll { float v[1105]; };
constexpr CGAll make_cg() {
  CGAll R{};
  for (int t = 0; t < 19; ++t) {
    const int l1 = T_L1c[t], l2 = T_L2c[t], l3 = T_L3c[t], off = T_OFFc[t];
    const int d1 = 2 * l1 + 1, d2 = 2 * l2 + 1, d3 = 2 * l3 + 1;
    double tmp[175] = {};
    for (int i = 0; i < d1; ++i) {
      const int m1 = i - l1;
      const Row r1 = c2r_row(l1, i);
      for (int k = 0; k < d2; ++k) {
        const int m2 = k - l2, m3 = m1 + m2;
        if (m3 < -l3 || m3 > l3) continue;
        const double cc = su2cg(l1, m1, l2, m2, l3, m3);
        if (cc == 0.0) continue;
        const Row r2 = c2r_row(l2, k);
        const Row r3 = c2r_row(l3, m3 + l3);
        for (int a = 0; a < r1.cnt; ++a)
          for (int b = 0; b < r2.cnt; ++b) {
            const Cx q12 = cxmul(r1.v[a], r2.v[b]);
            for (int cdx = 0; cdx < r3.cnt; ++cdx) {
              const double re = q12.re * r3.v[cdx].re + q12.im * r3.v[cdx].im;
              tmp[(r1.col[a] * d2 + r2.col[b]) * d3 + r3.col[cdx]] += re * cc;
            }
          }
      }
    }
    const int sz = d1 * d2 * d3;
    for (int e = 0; e < sz; ++e) R.v[off + e] = (float)tmp[e];
  }
  return R;
}
constexpr CGAll CG_ALL = make_cg();

constexpr bool check_cg_sym() {
  for (int t = 0; t < 18; ++t) {
    const int tc = TT_CANONc[t];
    if (tc == t) continue;
    const int l1 = K_L1c[t], l2 = K_L2c[t], l12 = K_L12c[t];
    const int d1 = 2*l1+1, d2 = 2*l2+1, d12 = 2*l12+1;
    for (int i = 0; i < d1; ++i)
      for (int j = 0; j < d2; ++j)
        for (int k = 0; k < d12; ++k) {
          float a = CG_ALL.v[T_OFFc[t]  + (i*d2 + j)*d12 + k];
          float b = TT_SGNc[t] * CG_ALL.v[T_OFFc[tc] + (j*d1 + i)*d12 + k];
          float d = a - b; if (d < 0) d = -d;
          if (d > 1e-5f) return false;
        }
  }
  return true;
}
static_assert(check_cg_sym(), "CG exchange symmetry violated");

// ============================ weight pack kernel ===============================
// wt[E][31 slots][64 cp] float4 = {ordA@ch0, ordB@ch0, ordA@ch1, ordB@ch1}
// where ordA/ordB = PK.ord[2s], PK.ord[2s+1]. Lanes = cp -> reads stride-8B
// dense per source row, writes perfectly coalesced. 317 KB total.
__global__ __launch_bounds__(256) void epb_wt(
    const float* __restrict__ w1,   // [E, 2, C]
    const float* __restrict__ w2,   // [E, 9, C]
    const float* __restrict__ w3,   // [E, 51, C]
    float4* __restrict__ wt)        // [E, 31, 64]
{
  const int idx = blockIdx.x * 256 + threadIdx.x;   // (e*31 + slot)*64 + cp
  if (idx >= NE * 31 * 64) return;
  const int cp   = idx & 63;
  const int slot = (idx >> 6) % 31;
  const int e    = (idx >> 6) / 31;
  const int pa = PK.ord[2 * slot], pb = PK.ord[2 * slot + 1];
  auto src = [&](int pi, int c) -> float {
    if (pi < 2)  return w1[((size_t)e * 2  + pi)        * NC + c];
    if (pi < 11) return w2[((size_t)e * 9  + (pi - 2))  * NC + c];
    return              w3[((size_t)e * 51 + (pi - 11)) * NC + c];
  };
  wt[idx] = make_float4(src(pa, 2 * cp),     src(pb, 2 * cp),
                        src(pa, 2 * cp + 1), src(pb, 2 * cp + 1));
}

// ============================ fused basis + linear kernel ======================
// Block = 4 nodes x 256 threads (R20 structure). Phase A: wave nl owns node
// nb+nl, lanes own channel pairs; nf via 5 vector loads; weights via 31
// sequential coalesced dwordx4 slots (consumption-ordered). B -> 8KB LDS.
// Phase B: identical to R20 (batched W prefetch, Red reduce).
__global__ __launch_bounds__(256) void epb_fused(
    const float*  __restrict__ nf,      // [N, C, 9]
    const float4* __restrict__ wt,      // [E, 31, 64] packed weights
    const float4* __restrict__ lw0_4,   // [C, F/4]
    const float4* __restrict__ lw1_4,   // [C, F/4]
    const int*    __restrict__ species, // [N]
    float* __restrict__ out)            // [N, F, 4]
{
  __shared__ float4 Bsh[4 * NC];        //  8 KB  [node][channel] (m0..m3)
  __shared__ float4 Red[16 * NC];       // 32 KB  [node*4+f_local][chunk*32+q]

  const int t  = threadIdx.x;
  const int nb = blockIdx.x * 4;

  // ---------------- phase A: basis (math unchanged; loads restructured) ----
  {
    const int nl = t >> 6;               // wave-uniform node
    const int cp = t & 63;               // channel pair
    const int c0 = cp * 2;
    const int n  = nb + nl;
    const int s  = species[n];

    // nf: per-thread 72 contiguous bytes -> 4x dwordx4 + 1x dwordx2
    const float* ap = nf + ((size_t)n * NC + c0) * 9;
    v2f A[9];
    {
      const f4u v0 = *reinterpret_cast<const f4u*>(ap);        // ap[0..3]
      const f4u v1 = *reinterpret_cast<const f4u*>(ap + 4);    // ap[4..7]
      const f4u v2 = *reinterpret_cast<const f4u*>(ap + 8);    // ap[8..11]
      const f4u v3 = *reinterpret_cast<const f4u*>(ap + 12);   // ap[12..15]
      const v2f v4 = ld2(ap + 16);                             // ap[16..17]
      A[0] = v2f{v0[0], v2[1]}; A[1] = v2f{v0[1], v2[2]}; A[2] = v2f{v0[2], v2[3]};
      A[3] = v2f{v0[3], v3[0]}; A[4] = v2f{v1[0], v3[1]}; A[5] = v2f{v1[1], v3[2]};
      A[6] = v2f{v1[2], v3[3]}; A[7] = v2f{v1[3], v4.x};  A[8] = v2f{v2[0], v4.y};
    }

    // packed weights: slot loads are coalesced dwordx4, consumption-ordered
    const float4* wtp = wt + (size_t)s * 31 * 64 + cp;
    auto getw = [&](auto PI) -> v2f {
      constexpr int pos = PK.pos[PI.value];
      const float4 q = wtp[(pos >> 1) * 64];
      if constexpr (pos & 1) return v2f{q.y, q.w};
      else                   return v2f{q.x, q.z};
    };

    v2f B[4];
    {
      const v2f wa = getw(std::integral_constant<int, 0>{});
      const v2f wb = getw(std::integral_constant<int, 1>{});
      B[0] = wa * A[0];
      B[1] = wb * A[1];
      B[2] = wb * A[2];
      B[3] = wb * A[3];
    }

    sfor<7>([&](auto P) {
      constexpr int p  = P.value;
      constexpr int l1 = P2U_L1c[p], l2 = P2U_L2c[p], lo = P2U_LOc[p];
      constexpr int d1 = 2*l1+1, d2 = 2*l2+1, dl = 2*lo+1;
      constexpr int off = T_OFFc[P2U_TBLc[p]];
      v2f w = getw(std::integral_constant<int, 2 + P2U_WAc[p]>{});
      if constexpr (P2U_WBc[p] >= 0)
        w = w + getw(std::integral_constant<int, 2 + P2U_WBc[p]>{});
      sfor<dl>([&](auto Kk) {
        constexpr int k = Kk.value;
        v2f v = {0.f, 0.f};
        sfor<d1>([&](auto I) {
          sfor<d2>([&](auto J) {
            constexpr float cgc = CG_ALL.v[off + (I.value * d2 + J.value) * dl + k];
            if constexpr (cgc != 0.0f) {
              constexpr int ia = AOFFc[l1] + I.value, ja = AOFFc[l2] + J.value;
              constexpr int x = ia < ja ? ia : ja, y = ia < ja ? ja : ia;
              v = cfma(cgc, A[x] * A[y], v);
            }
          });
        });
        B[lo + k] = vfma(w, v, B[lo + k]);
      });
    });

    sfor<13>([&](auto CI) {
      constexpr int tk  = CANONc[CI.value];
      constexpr int l1  = K_L1c[tk], l2 = K_L2c[tk], l12 = K_L12c[tk];
      constexpr int d1  = 2*l1+1, d2 = 2*l2+1, d12 = 2*l12+1;
      constexpr int off = T_OFFc[tk];
      v2f tt[d12];
      sfor<d12>([&](auto Kk) {
        constexpr int k = Kk.value;
        v2f v = {0.f, 0.f};
        sfor<d1>([&](auto I) {
          sfor<d2>([&](auto J) {
            constexpr float cgc = CG_ALL.v[off + (I.value * d2 + J.value) * d12 + k];
            if constexpr (cgc != 0.0f) {
              constexpr int ia = AOFFc[l1] + I.value, ja = AOFFc[l2] + J.value;
              constexpr int x = ia < ja ? ia : ja, y = ia < ja ? ja : ia;
              v = cfma(cgc, A[x] * A[y], v);
            }
          });
        });
        tt[k] = v;
      });

      auto consume = [&](auto TK, auto SG) {
        constexpr int tkey = TK.value;
        constexpr float sgn = (float)SG.value;
        constexpr int pcnt = P3_STARTc[tkey + 1] - P3_STARTc[tkey];
        sfor<pcnt>([&](auto PP) {
          constexpr int p  = P3_STARTc[tkey] + PP.value;
          constexpr int l3 = P3_L3c[p], lo = P3_LOc[p];
          constexpr int d3 = 2*l3+1, dl = 2*lo+1;
          constexpr int off2 = T_OFFc[P3_TBLc[p]];
          const v2f w = getw(std::integral_constant<int, 11 + p>{});
          sfor<dl>([&](auto M) {
            v2f v = {0.f, 0.f};
            sfor<d12>([&](auto Kk) {
              sfor<d3>([&](auto J) {
                constexpr float cgc = sgn * CG_ALL.v[off2 + (Kk.value * d3 + J.value) * dl + M.value];
                if constexpr (cgc != 0.0f)
                  v = cfma(cgc, tt[Kk.value] * A[AOFFc[l3] + J.value], v);
              });
            });
            B[lo + M.value] = vfma(w, v, B[lo + M.value]);
          });
        });
      };
      consume(std::integral_constant<int, tk>{}, std::integral_constant<int, 1>{});
      constexpr int td = CONS2c[CI.value];
      if constexpr (td >= 0)
        consume(std::integral_constant<int, td>{},
                std::integral_constant<int, (int)TT_SGNc[td]>{});
    });

    Bsh[nl * NC + c0]     = make_float4(B[0].x, B[1].x, B[2].x, B[3].x);
    Bsh[nl * NC + c0 + 1] = make_float4(B[0].y, B[1].y, B[2].y, B[3].y);
  }
  __syncthreads();

  // ---------------- phase B: equivariant linear (R20, batched W prefetch) --
  const int q   = t & 31;
  const int dup = (t >> 5) & 1;
  const int wv  = t >> 6;
  const int n0  = dup * 2;

  float4 acc[2][4] = {};                 // [node-in-pair][f_local]

  const float4* w0c = lw0_4 + (size_t)(wv * 32) * 32 + q;
  const float4* w1c = lw1_4 + (size_t)(wv * 32) * 32 + q;
  const float4* bp0 = &Bsh[ n0      * NC + wv * 32];
  const float4* bp1 = &Bsh[(n0 + 1) * NC + wv * 32];

  #pragma unroll 1
  for (int g = 0; g < 4; ++g) {
    float4 wA[8], wB[8];
    sfor<8>([&](auto I) {
      wA[I.value] = w0c[(size_t)(g * 8 + I.value) * 32];
      wB[I.value] = w1c[(size_t)(g * 8 + I.value) * 32];
    });
    sfor<8>([&](auto I) {
      const int i = g * 8 + I.value;
      const float4 wa = wA[I.value];
      const float4 wb = wB[I.value];
      const float4 ba = bp0[i];
      const float4 bb = bp1[i];
#define FQ(f, waf, wbf) \
      acc[0][f].x = fmaf(ba.x, waf, acc[0][f].x); \
      acc[0][f].y = fmaf(ba.y, wbf, acc[0][f].y); \
      acc[0][f].z = fmaf(ba.z, wbf, acc[0][f].z); \
      acc[0][f].w = fmaf(ba.w, wbf, acc[0][f].w); \
      acc[1][f].x = fmaf(bb.x, waf, acc[1][f].x); \
      acc[1][f].y = fmaf(bb.y, wbf, acc[1][f].y); \
      acc[1][f].z = fmaf(bb.z, wbf, acc[1][f].z); \
      acc[1][f].w = fmaf(bb.w, wbf, acc[1][f].w);
      FQ(0, wa.x, wb.x)
      FQ(1, wa.y, wb.y)
      FQ(2, wa.z, wb.z)
      FQ(3, wa.w, wb.w)
#undef FQ
    });
  }

  sfor<2>([&](auto NN_) {
    sfor<4>([&](auto F_) {
      Red[((n0 + NN_.value) * 4 + F_.value) * NC + wv * 32 + q] = acc[NN_.value][F_.value];
    });
  });
  __syncthreads();

  const float s4 = 0.08838834764831845f;  // 1/sqrt(128)
  float4* o4 = reinterpret_cast<float4*>(out);
  sfor<2>([&](auto O_) {
    const int oid = 2 * t + O_.value;     // 0..511 = 4 nodes x 128 features
    const int n   = oid >> 7;
    const int rem = oid & 127;            // feature index
    const int row = (n * 4 + (rem & 3)) * NC + (rem >> 2);
    const float4 r0 = Red[row];
    const float4 r1 = Red[row + 32];
    const float4 r2 = Red[row + 64];
    const float4 r3 = Red[row + 96];
    o4[(size_t)(nb + n) * NC + rem] = make_float4(
        ((r0.x + r1.x) + (r2.x + r3.x)) * s4,
        ((r0.y + r1.y) + (r2.y + r3.y)) * s4,
        ((r0.z + r1.z) + (r2.z + r3.z)) * s4,
        ((r0.w + r1.w) + (r2.w + r3.w)) * s4);
  });
}

// ------------------------------- launcher --------------------------------------
extern "C" void kernel_launch(void* const* d_in, const int* in_sizes, int n_in,
                              void* d_out, int out_size, void* d_ws, size_t ws_size,
                              hipStream_t stream) {
  const float* nf  = (const float*)d_in[0];
  const float* w1  = (const float*)d_in[1];
  const float* w2  = (const float*)d_in[2];
  const float* w3  = (const float*)d_in[3];
  const float* lw0 = (const float*)d_in[4];
  const float* lw1 = (const float*)d_in[5];
  const int*   spc = (const int*)  d_in[6];
  float* out = (float*)d_out;
  float4* wt = (float4*)d_ws;           // [E, 31, 64] float4 = 317 KB
  (void)ws_size; (void)in_sizes; (void)n_in; (void)out_size;

  hipLaunchKernelGGL(epb_wt, dim3((NE * 31 * 64 + 255) / 256), dim3(256), 0,
                     stream, w1, w2, w3, wt);
  hipLaunchKernelGGL(epb_fused, dim3(NN / 4), dim3(256), 0, stream,
                     nf, wt, (const float4*)lw0, (const float4*)lw1,
                     spc, out);
}

// Round 11
// 97.557 us; speedup vs baseline: 1.0152x; 1.0152x over previous
//
#include <hip/hip_runtime.h>
#include <utility>

// EquivariantProductBasisBlock (MACE-style) for gfx950 — round 22.
// R21 post-mortem: consumption-ordered weight packing + extra launch = net
// null (99.04 vs R20 98.04) -> original [paths][C] weight layout was
// already lane-coalesced; compiler hoist depth (VGPR-bound) is the real
// limit, address order irrelevant. Keep nf vectorization (validated), drop
// packing + wt kernel.
// R22 = R20 + two changes: (1) nf 18 scalar -> 4x dwordx4 + 1x dwordx2;
// (2) phase B W-prefetch ping-pong: 8 groups of 4 c-iters, consume group g
// WHILE group g+1's 8 float4 loads are in flight. VGPR-NEUTRAL vs R20
// (2x8 float4 buffers = 64 regs = R20's 1x16) -> no occupancy/spill risk
// (R13/R15 lessons). Math order identical -> absmax unchanged.
// Predict: VGPR 110-125 (<128 cliff), kernel 37.5 -> ~32-34us, dur ~94-96.
// Falsifier: null -> phase B not load-latency-bound; next = split probe.

#define NN 4096
#define NC 128
#define NE 10

typedef float v2f __attribute__((ext_vector_type(2)));
typedef float f4u __attribute__((ext_vector_type(4), aligned(4)));

__device__ __forceinline__ v2f ld2(const float* p) {
  return *reinterpret_cast<const v2f*>(p);
}
__device__ __forceinline__ v2f cfma(float c, v2f x, v2f a) {  // a += c*x (splat c)
  v2f cc = {c, c};
  return __builtin_elementwise_fma(cc, x, a);
}
__device__ __forceinline__ v2f vfma(v2f w, v2f x, v2f a) {    // a += w*x
  return __builtin_elementwise_fma(w, x, a);
}

// ---------------------------- static_for ---------------------------------------
template<typename F, int... Is>
__device__ __forceinline__ void sfor_impl(F&& f, std::integer_sequence<int, Is...>) {
  (f(std::integral_constant<int, Is>{}), ...);
}
template<int N, typename F>
__device__ __forceinline__ void sfor(F&& f) {
  sfor_impl((F&&)f, std::make_integer_sequence<int, N>{});
}

// ---------------------------- CG metadata (constexpr) --------------------------
constexpr int T_L1c[19]  = {0,0,0,1,1,1,1,1,1,1,2,2,2,2,2,2,2,2,3};
constexpr int T_L2c[19]  = {0,1,2,0,1,1,1,2,2,2,0,1,1,1,2,2,2,2,2};
constexpr int T_L3c[19]  = {0,1,2,1,0,1,2,1,2,3,2,1,2,3,0,1,2,3,1};
constexpr int T_OFFc[19] = {0,1,10,35,44,53,80,125,170,245,350,375,420,495,600,625,700,825,1000};
constexpr int AOFFc[3]   = {0,1,4};

constexpr int P2U_L1c[7]  = {0,0,1,1,1,2,2};
constexpr int P2U_L2c[7]  = {0,1,1,1,2,2,2};
constexpr int P2U_LOc[7]  = {0,1,0,1,1,0,1};
constexpr int P2U_TBLc[7] = {0,1,4,5,7,14,15};
constexpr int P2U_WAc[7]  = {0,1,3,4,5,7,8};
constexpr int P2U_WBc[7]  = {-1,2,-1,-1,6,-1,-1};

constexpr int K_L1c[18]  = {0,0,0,1,1,1,1,1,1,1,2,2,2,2,2,2,2,2};
constexpr int K_L2c[18]  = {0,1,2,0,1,1,1,2,2,2,0,1,1,1,2,2,2,2};
constexpr int K_L12c[18] = {0,1,2,1,0,1,2,1,2,3,2,1,2,3,0,1,2,3};

constexpr int   TT_CANONc[18] = {0,1,2,1,4,5,6,7,8,9,2,7,8,9,14,15,16,17};
constexpr float TT_SGNc[18]   = {1,1,1,1,1,1,1,1,1,1,1,1,-1,1,1,1,1,1};
constexpr int CANONc[13] = {0,1,2,4,5,6,7,8,9,14,15,16,17};
constexpr int CONS2c[13] = {-1,3,10,-1,-1,-1,11,12,13,-1,-1,-1,-1};

constexpr int P3_STARTc[19] = {0,2,6,9,13,15,19,22,26,29,30,33,37,40,41,43,47,50,51};
constexpr int P3_L3c[51] = {
  0,1,  0,1,1,2,  1,2,2,  0,1,1,2,  0,1,  0,1,1,2,  1,2,2,  0,1,1,2,  1,2,2,
  2,  1,2,2,  0,1,1,2,  1,2,2,  2,  0,1,  0,1,1,2,  1,2,2,  2 };
constexpr int P3_LOc[51] = {
  0,1,  1,0,1,1,  1,0,1,  1,0,1,1,  0,1,  1,0,1,1,  1,0,1,  1,0,1,1,  1,0,1,
  1,  1,0,1,  1,0,1,1,  1,0,1,  1,  0,1,  1,0,1,1,  1,0,1,  1 };
constexpr int P3_TBLc[51] = {
  0,1,  3,4,5,7,  11,14,15,  3,4,5,7,  0,1,  3,4,5,7,  11,14,15,  3,4,5,7,
  11,14,15,  18,  11,14,15,  3,4,5,7,  11,14,15,  18,  0,1,  3,4,5,7,
  11,14,15,  18 };

// ---------------------------- constexpr CG computation -------------------------
constexpr double cfact(int n) { double r = 1.0; for (int i = 2; i <= n; ++i) r *= i; return r; }
constexpr double csqrt(double x) {
  if (x <= 0.0) return 0.0;
  double r = x > 1.0 ? x : 1.0;
  for (int i = 0; i < 64; ++i) r = 0.5 * (r + x / r);
  return r;
}
constexpr double su2cg(int j1, int m1, int j2, int m2, int j3, int m3) {
  if (m3 != m1 + m2) return 0.0;
  int vmin = -j1 + j2 + m3; if (-j1 + m1 > vmin) vmin = -j1 + m1; if (vmin < 0) vmin = 0;
  int vmax = j2 + j3 + m1; if (j3 - j1 + j2 < vmax) vmax = j3 - j1 + j2; if (j3 + m3 < vmax) vmax = j3 + m3;
  double C = csqrt((2.0 * j3 + 1.0)
                   * cfact(j3 + j1 - j2) * cfact(j3 - j1 + j2) * cfact(j1 + j2 - j3)
                   * cfact(j3 + m3) * cfact(j3 - m3)
                   / (cfact(j1 + j2 + j3 + 1) * cfact(j1 - m1) * cfact(j1 + m1)
                      * cfact(j2 - m2) * cfact(j2 + m2)));
  double S = 0.0;
  for (int v = vmin; v <= vmax; ++v) {
    double sgn = ((v + j2 + m2) & 1) ? -1.0 : 1.0;
    S += sgn * cfact(j2 + j3 + m1 - v) * cfact(j1 - m1 + v)
         / (cfact(v) * cfact(j3 - j1 + j2 - v) * cfact(j3 + m3 - v) * cfact(v + j1 - j2 - m3));
  }
  return C * S;
}

struct Cx { double re, im; };
constexpr Cx cxmul(Cx a, Cx b) { return Cx{a.re * b.re - a.im * b.im, a.re * b.im + a.im * b.re}; }
struct Row { int cnt; int col[2]; Cx v[2]; };

constexpr Row c2r_row(int l, int r) {
  Row out{0, {0, 0}, {{0, 0}, {0, 0}}};
  constexpr double is2 = 0.70710678118654752440;
  const int m = r - l;
  if (m < 0) {
    out.cnt = 2;
    out.col[0] = l - m; out.v[0] = Cx{is2, 0.0};
    out.col[1] = l + m; out.v[1] = Cx{0.0, -is2};
  } else if (m == 0) {
    out.cnt = 1; out.col[0] = l; out.v[0] = Cx{1.0, 0.0};
  } else {
    const double sgn = (m & 1) ? -1.0 : 1.0;
    out.cnt = 2;
    out.col[0] = l + m; out.v[0] = Cx{sgn * is2, 0.0};
    out.col[1] = l - m; out.v[1] = Cx{0.0, sgn * is2};
  }
  const int ph = l & 3;
  for (int a = 0; a < out.cnt; ++a) {
    Cx v = out.v[a];
    out.v[a] = (ph == 0) ? v
             : (ph == 1) ? Cx{v.im, -v.re}
             : (ph == 2) ? Cx{-v.re, -v.im}
                         : Cx{-v.im, v.re};
  }
  return out;
}

struct CGAll { float v[1105]; };
constexpr CGAll make_cg() {
  CGAll R{};
  for (int t = 0; t < 19; ++t) {
    const int l1 = T_L1c[t], l2 = T_L2c[t], l3 = T_L3c[t], off = T_OFFc[t];
    const int d1 = 2 * l1 + 1, d2 = 2 * l2 + 1, d3 = 2 * l3 + 1;
    double tmp[175] = {};
    for (int i = 0; i < d1; ++i) {
      const int m1 = i - l1;
      const Row r1 = c2r_row(l1, i);
      for (int k = 0; k < d2; ++k) {
        const int m2 = k - l2, m3 = m1 + m2;
        if (m3 < -l3 || m3 > l3) continue;
        const double cc = su2cg(l1, m1, l2, m2, l3, m3);
        if (cc == 0.0) continue;
        const Row r2 = c2r_row(l2, k);
        const Row r3 = c2r_row(l3, m3 + l3);
        for (int a = 0; a < r1.cnt; ++a)
          for (int b = 0; b < r2.cnt; ++b) {
            const Cx q12 = cxmul(r1.v[a], r2.v[b]);
            for (int cdx = 0; cdx < r3.cnt; ++cdx) {
              const double re = q12.re * r3.v[cdx].re + q12.im * r3.v[cdx].im;
              tmp[(r1.col[a] * d2 + r2.col[b]) * d3 + r3.col[cdx]] += re * cc;
            }
          }
      }
    }
    const int sz = d1 * d2 * d3;
    for (int e = 0; e < sz; ++e) R.v[off + e] = (float)tmp[e];
  }
  return R;
}
constexpr CGAll CG_ALL = make_cg();

constexpr bool check_cg_sym() {
  for (int t = 0; t < 18; ++t) {
    const int tc = TT_CANONc[t];
    if (tc == t) continue;
    const int l1 = K_L1c[t], l2 = K_L2c[t], l12 = K_L12c[t];
    const int d1 = 2*l1+1, d2 = 2*l2+1, d12 = 2*l12+1;
    for (int i = 0; i < d1; ++i)
      for (int j = 0; j < d2; ++j)
        for (int k = 0; k < d12; ++k) {
          float a = CG_ALL.v[T_OFFc[t]  + (i*d2 + j)*d12 + k];
          float b = TT_SGNc[t] * CG_ALL.v[T_OFFc[tc] + (j*d1 + i)*d12 + k];
          float d = a - b; if (d < 0) d = -d;
          if (d > 1e-5f) return false;
        }
  }
  return true;
}
static_assert(check_cg_sym(), "CG exchange symmetry violated");

// ============================ fused basis + linear kernel ======================
// Block = 4 nodes x 256 threads (R20 structure). Phase A: wave nl owns node
// nb+nl, lanes own channel pairs; nf via 5 vector loads; weights via the
// original coalesced [paths][C] pointers. B -> 8KB LDS. Phase B: ping-pong
// double-buffered W prefetch (8 groups x 4 c-iters), Red reduce, store.
__global__ __launch_bounds__(256) void epb_fused(
    const float*  __restrict__ nf,      // [N, C, 9]
    const float*  __restrict__ w1,      // [E, 2, C]
    const float*  __restrict__ w2,      // [E, 9, C]
    const float*  __restrict__ w3,      // [E, 51, C]
    const float4* __restrict__ lw0_4,   // [C, F/4]
    const float4* __restrict__ lw1_4,   // [C, F/4]
    const int*    __restrict__ species, // [N]
    float* __restrict__ out)            // [N, F, 4]
{
  __shared__ float4 Bsh[4 * NC];        //  8 KB  [node][channel] (m0..m3)
  __shared__ float4 Red[16 * NC];       // 32 KB  [node*4+f_local][chunk*32+q]

  const int t  = threadIdx.x;
  const int nb = blockIdx.x * 4;

  // ---------------- phase A: basis (math unchanged from R9) ----------------
  {
    const int nl = t >> 6;               // wave-uniform node
    const int c0 = (t & 63) * 2;         // channel pair
    const int n  = nb + nl;
    const int s  = species[n];

    // nf: per-thread 72 contiguous bytes -> 4x dwordx4 + 1x dwordx2 (R21-validated)
    const float* ap = nf + ((size_t)n * NC + c0) * 9;
    v2f A[9];
    {
      const f4u v0 = *reinterpret_cast<const f4u*>(ap);        // ap[0..3]
      const f4u v1 = *reinterpret_cast<const f4u*>(ap + 4);    // ap[4..7]
      const f4u v2 = *reinterpret_cast<const f4u*>(ap + 8);    // ap[8..11]
      const f4u v3 = *reinterpret_cast<const f4u*>(ap + 12);   // ap[12..15]
      const v2f v4 = ld2(ap + 16);                             // ap[16..17]
      A[0] = v2f{v0[0], v2[1]}; A[1] = v2f{v0[1], v2[2]}; A[2] = v2f{v0[2], v2[3]};
      A[3] = v2f{v0[3], v3[0]}; A[4] = v2f{v1[0], v3[1]}; A[5] = v2f{v1[1], v3[2]};
      A[6] = v2f{v1[2], v3[3]}; A[7] = v2f{v1[3], v4.x};  A[8] = v2f{v2[0], v4.y};
    }

    const float* w1p = w1 + (size_t)s * 2  * NC + c0;
    const float* w2p = w2 + (size_t)s * 9  * NC + c0;
    const float* w3p = w3 + (size_t)s * 51 * NC + c0;

    v2f B[4];
    {
      const v2f wa = ld2(w1p), wb = ld2(w1p + NC);
      B[0] = wa * A[0];
      B[1] = wb * A[1];
      B[2] = wb * A[2];
      B[3] = wb * A[3];
    }

    sfor<7>([&](auto P) {
      constexpr int p  = P.value;
      constexpr int l1 = P2U_L1c[p], l2 = P2U_L2c[p], lo = P2U_LOc[p];
      constexpr int d1 = 2*l1+1, d2 = 2*l2+1, dl = 2*lo+1;
      constexpr int off = T_OFFc[P2U_TBLc[p]];
      v2f w = ld2(w2p + P2U_WAc[p] * NC);
      if constexpr (P2U_WBc[p] >= 0) w = w + ld2(w2p + P2U_WBc[p] * NC);
      sfor<dl>([&](auto Kk) {
        constexpr int k = Kk.value;
        v2f v = {0.f, 0.f};
        sfor<d1>([&](auto I) {
          sfor<d2>([&](auto J) {
            constexpr float cgc = CG_ALL.v[off + (I.value * d2 + J.value) * dl + k];
            if constexpr (cgc != 0.0f) {
              constexpr int ia = AOFFc[l1] + I.value, ja = AOFFc[l2] + J.value;
              constexpr int x = ia < ja ? ia : ja, y = ia < ja ? ja : ia;
              v = cfma(cgc, A[x] * A[y], v);
            }
          });
        });
        B[lo + k] = vfma(w, v, B[lo + k]);
      });
    });

    sfor<13>([&](auto CI) {
      constexpr int tk  = CANONc[CI.value];
      constexpr int l1  = K_L1c[tk], l2 = K_L2c[tk], l12 = K_L12c[tk];
      constexpr int d1  = 2*l1+1, d2 = 2*l2+1, d12 = 2*l12+1;
      constexpr int off = T_OFFc[tk];
      v2f tt[d12];
      sfor<d12>([&](auto Kk) {
        constexpr int k = Kk.value;
        v2f v = {0.f, 0.f};
        sfor<d1>([&](auto I) {
          sfor<d2>([&](auto J) {
            constexpr float cgc = CG_ALL.v[off + (I.value * d2 + J.value) * d12 + k];
            if constexpr (cgc != 0.0f) {
              constexpr int ia = AOFFc[l1] + I.value, ja = AOFFc[l2] + J.value;
              constexpr int x = ia < ja ? ia : ja, y = ia < ja ? ja : ia;
              v = cfma(cgc, A[x] * A[y], v);
            }
          });
        });
        tt[k] = v;
      });

      auto consume = [&](auto TK, auto SG) {
        constexpr int tkey = TK.value;
        constexpr float sgn = (float)SG.value;
        constexpr int pcnt = P3_STARTc[tkey + 1] - P3_STARTc[tkey];
        sfor<pcnt>([&](auto PP) {
          constexpr int p  = P3_STARTc[tkey] + PP.value;
          constexpr int l3 = P3_L3c[p], lo = P3_LOc[p];
          constexpr int d3 = 2*l3+1, dl = 2*lo+1;
          constexpr int off2 = T_OFFc[P3_TBLc[p]];
          const v2f w = ld2(w3p + p * NC);
          sfor<dl>([&](auto M) {
            v2f v = {0.f, 0.f};
            sfor<d12>([&](auto Kk) {
              sfor<d3>([&](auto J) {
                constexpr float cgc = sgn * CG_ALL.v[off2 + (Kk.value * d3 + J.value) * dl + M.value];
                if constexpr (cgc != 0.0f)
                  v = cfma(cgc, tt[Kk.value] * A[AOFFc[l3] + J.value], v);
              });
            });
            B[lo + M.value] = vfma(w, v, B[lo + M.value]);
          });
        });
      };
      consume(std::integral_constant<int, tk>{}, std::integral_constant<int, 1>{});
      constexpr int td = CONS2c[CI.value];
      if constexpr (td >= 0)
        consume(std::integral_constant<int, td>{},
                std::integral_constant<int, (int)TT_SGNc[td]>{});
    });

    Bsh[nl * NC + c0]     = make_float4(B[0].x, B[1].x, B[2].x, B[3].x);
    Bsh[nl * NC + c0 + 1] = make_float4(B[0].y, B[1].y, B[2].y, B[3].y);
  }
  __syncthreads();

  // ---------------- phase B: equivariant linear (ping-pong W prefetch) -----
  // thread -> (q = f-quad 0..31, dup = node-pair 0/1, wv = 32-ch chunk 0..3)
  const int q   = t & 31;
  const int dup = (t >> 5) & 1;
  const int wv  = t >> 6;
  const int n0  = dup * 2;

  float4 acc[2][4] = {};                 // [node-in-pair][f_local]

  const float4* w0c = lw0_4 + (size_t)(wv * 32) * 32 + q;
  const float4* w1c = lw1_4 + (size_t)(wv * 32) * 32 + q;
  const float4* bp0 = &Bsh[ n0      * NC + wv * 32];
  const float4* bp1 = &Bsh[(n0 + 1) * NC + wv * 32];

  // 8 groups of 4 c-iters, double-buffered: consume group g while group
  // g+1's 8 float4 loads are in flight. VGPR-neutral vs R20 (2x8 = 1x16).
  float4 wA0[4], wB0[4], wA1[4], wB1[4];

#define LOADG(bufA, bufB, g) \
  sfor<4>([&](auto I_) { \
    bufA[I_.value] = w0c[(size_t)((g) * 4 + I_.value) * 32]; \
    bufB[I_.value] = w1c[(size_t)((g) * 4 + I_.value) * 32]; \
  });

#define CONSUME(bufA, bufB, g) \
  sfor<4>([&](auto I_) { \
    const int i = (g) * 4 + I_.value; \
    const float4 wa = bufA[I_.value]; \
    const float4 wb = bufB[I_.value]; \
    const float4 ba = bp0[i]; \
    const float4 bb = bp1[i]; \
    acc[0][0].x = fmaf(ba.x, wa.x, acc[0][0].x); \
    acc[0][0].y = fmaf(ba.y, wb.x, acc[0][0].y); \
    acc[0][0].z = fmaf(ba.z, wb.x, acc[0][0].z); \
    acc[0][0].w = fmaf(ba.w, wb.x, acc[0][0].w); \
    acc[1][0].x = fmaf(bb.x, wa.x, acc[1][0].x); \
    acc[1][0].y = fmaf(bb.y, wb.x, acc[1][0].y); \
    acc[1][0].z = fmaf(bb.z, wb.x, acc[1][0].z); \
    acc[1][0].w = fmaf(bb.w, wb.x, acc[1][0].w); \
    acc[0][1].x = fmaf(ba.x, wa.y, acc[0][1].x); \
    acc[0][1].y = fmaf(ba.y, wb.y, acc[0][1].y); \
    acc[0][1].z = fmaf(ba.z, wb.y, acc[0][1].z); \
    acc[0][1].w = fmaf(ba.w, wb.y, acc[0][1].w); \
    acc[1][1].x = fmaf(bb.x, wa.y, acc[1][1].x); \
    acc[1][1].y = fmaf(bb.y, wb.y, acc[1][1].y); \
    acc[1][1].z = fmaf(bb.z, wb.y, acc[1][1].z); \
    acc[1][1].w = fmaf(bb.w, wb.y, acc[1][1].w); \
    acc[0][2].x = fmaf(ba.x, wa.z, acc[0][2].x); \
    acc[0][2].y = fmaf(ba.y, wb.z, acc[0][2].y); \
    acc[0][2].z = fmaf(ba.z, wb.z, acc[0][2].z); \
    acc[0][2].w = fmaf(ba.w, wb.z, acc[0][2].w); \
    acc[1][2].x = fmaf(bb.x, wa.z, acc[1][2].x); \
    acc[1][2].y = fmaf(bb.y, wb.z, acc[1][2].y); \
    acc[1][2].z = fmaf(bb.z, wb.z, acc[1][2].z); \
    acc[1][2].w = fmaf(bb.w, wb.z, acc[1][2].w); \
    acc[0][3].x = fmaf(ba.x, wa.w, acc[0][3].x); \
    acc[0][3].y = fmaf(ba.y, wb.w, acc[0][3].y); \
    acc[0][3].z = fmaf(ba.z, wb.w, acc[0][3].z); \
    acc[0][3].w = fmaf(ba.w, wb.w, acc[0][3].w); \
    acc[1][3].x = fmaf(bb.x, wa.w, acc[1][3].x); \
    acc[1][3].y = fmaf(bb.y, wb.w, acc[1][3].y); \
    acc[1][3].z = fmaf(bb.z, wb.w, acc[1][3].z); \
    acc[1][3].w = fmaf(bb.w, wb.w, acc[1][3].w); \
  });

  LOADG(wA0, wB0, 0)
  #pragma unroll 1
  for (int gg = 0; gg < 4; ++gg) {
    const int g0 = 2 * gg;
    LOADG(wA1, wB1, g0 + 1)            // in flight while consuming g0
    CONSUME(wA0, wB0, g0)
    if (gg < 3) { LOADG(wA0, wB0, g0 + 2) }  // in flight while consuming g0+1
    CONSUME(wA1, wB1, g0 + 1)
  }
#undef LOADG
#undef CONSUME

  // partials to Red (unchanged from R20)
  sfor<2>([&](auto NN_) {
    sfor<4>([&](auto F_) {
      Red[((n0 + NN_.value) * 4 + F_.value) * NC + wv * 32 + q] = acc[NN_.value][F_.value];
    });
  });
  __syncthreads();

  // 4-way tree reduce + scale + coalesced store (2 float4 outputs per thread)
  const float s4 = 0.08838834764831845f;  // 1/sqrt(128)
  float4* o4 = reinterpret_cast<float4*>(out);
  sfor<2>([&](auto O_) {
    const int oid = 2 * t + O_.value;     // 0..511 = 4 nodes x 128 features
    const int n   = oid >> 7;
    const int rem = oid & 127;            // feature index
    const int row = (n * 4 + (rem & 3)) * NC + (rem >> 2);
    const float4 r0 = Red[row];
    const float4 r1 = Red[row + 32];
    const float4 r2 = Red[row + 64];
    const float4 r3 = Red[row + 96];
    o4[(size_t)(nb + n) * NC + rem] = make_float4(
        ((r0.x + r1.x) + (r2.x + r3.x)) * s4,
        ((r0.y + r1.y) + (r2.y + r3.y)) * s4,
        ((r0.z + r1.z) + (r2.z + r3.z)) * s4,
        ((r0.w + r1.w) + (r2.w + r3.w)) * s4);
  });
}

// ------------------------------- launcher --------------------------------------
extern "C" void kernel_launch(void* const* d_in, const int* in_sizes, int n_in,
                              void* d_out, int out_size, void* d_ws, size_t ws_size,
                              hipStream_t stream) {
  const float* nf  = (const float*)d_in[0];
  const float* w1  = (const float*)d_in[1];
  const float* w2  = (const float*)d_in[2];
  const float* w3  = (const float*)d_in[3];
  const float* lw0 = (const float*)d_in[4];
  const float* lw1 = (const float*)d_in[5];
  const int*   spc = (const int*)  d_in[6];
  float* out = (float*)d_out;
  (void)d_ws; (void)ws_size; (void)in_sizes; (void)n_in; (void)out_size;

  hipLaunchKernelGGL(epb_fused, dim3(NN / 4), dim3(256), 0, stream,
                     nf, w1, w2, w3, (const float4*)lw0, (const float4*)lw1,
                     spc, out);
}